// Round 20
// baseline (107.996 us; speedup 1.0000x reference)
//
#include <hip/hip_runtime.h>

// B=2, S=2048, E=1024, HEADS=16, HEAD_SIZE=64
// out = softmax((q Wq^T + bq)(k Wk^T + bk)^T / 32) (v Wv^T + bv) Wo^T + bo

typedef unsigned short u16;
typedef __bf16 bf16x8 __attribute__((ext_vector_type(8)));
typedef float f32x4 __attribute__((ext_vector_type(4)));
typedef u16 u16x4 __attribute__((ext_vector_type(4)));
typedef u16 u16x8 __attribute__((ext_vector_type(8)));

typedef __attribute__((address_space(1))) const unsigned int as1_cu32;
typedef __attribute__((address_space(3))) unsigned int as3_u32;

#if __has_builtin(__builtin_amdgcn_exp2f)
#define EXP2(x) __builtin_amdgcn_exp2f(x)   // raw v_exp_f32 (inputs are normal-range)
#else
#define EXP2(x) exp2f(x)
#endif

__device__ __forceinline__ u16 f2bf(float f) {
  unsigned u = __builtin_bit_cast(unsigned, f);
  u += 0x7fffu + ((u >> 16) & 1u);   // RTNE
  return (u16)(u >> 16);
}

__device__ __forceinline__ u16 bfc(float f) {   // RTNE via v_cvt (same bits as f2bf)
  return __builtin_bit_cast(u16, (__bf16)f);
}

__device__ __forceinline__ void gl_lds16(const u16* g, u16* l) {
  // async global->LDS, 16B/lane; LDS dest = wave-uniform base + lane*16
  __builtin_amdgcn_global_load_lds((as1_cu32*)g, (as3_u32*)l, 16, 0, 0);
}

// ---------------- fp32 -> bf16 cast (4 weight matrices only) ----------------
__global__ void cast_kernel(const float* __restrict__ wq, const float* __restrict__ wk,
                            const float* __restrict__ wv, const float* __restrict__ wo,
                            u16* __restrict__ wqb, u16* __restrict__ wkb,
                            u16* __restrict__ wvb, u16* __restrict__ wob) {
  unsigned t = blockIdx.x * 256u + threadIdx.x;  // 1M float4 = 4 x 256K
  unsigned which = t >> 18, off = t & 262143u;
  const float* src = which == 0 ? wq : (which == 1 ? wk : (which == 2 ? wv : wo));
  u16* dst = which == 0 ? wqb : (which == 1 ? wkb : (which == 2 ? wvb : wob));
  float4 f = ((const float4*)src)[off];
  u16x4 o;
  o[0] = f2bf(f.x); o[1] = f2bf(f.y); o[2] = f2bf(f.z); o[3] = f2bf(f.w);
  ((u16x4*)dst)[off] = o;
}

// ---------------- NT GEMM: C = scale*(A B^T + bias) ----------------
// BM x 128 tile, BK=64 (halves barrier count vs BK=32), 4 waves, 16x16x32 MFMA,
// dbuf LDS. Tile layout = attn-style: [row][128B], 8 x 16B chunks,
// phys_chunk = kchunk ^ (row&7) (measured-zero-conflict pattern).
// AREG: A source fp32; reg-staged (loads early, RTNE cvt, b128 writes late).
// MODE: 0 = bf16 row-major out, 1 = f32 row-major out,
// MODE 2 = bf16 V^T out [b,h,d,s] via LDS transpose + coalesced 16B stores.
template <int MODE, int BM, bool AREG>
__device__ __forceinline__ void gemm_body(const void* __restrict__ Av, const u16* __restrict__ B,
                                          const float* __restrict__ bias, void* __restrict__ Cv,
                                          float scale, char* SMraw) {
  constexpr int MI = BM / 32;                              // M frags per wave
  constexpr int ABUF = BM * 128;                           // bytes per A buffer
  constexpr int BBUF = 128 * 128;
  char* ASM = SMraw;
  char* BSM = SMraw + 2 * ABUF;
  constexpr int N = 1024, NK = 16;                         // K=1024 / BK=64
  const int m0 = blockIdx.x * BM;
  const int n0 = blockIdx.y * 128;
  const int tid = threadIdx.x;
  const int w = tid >> 6, l = tid & 63;
  const int lr = l & 15, lg = l >> 4;
  const int wm = (w >> 1) * (BM / 2), wn = (w & 1) * 64;

  // DMA staging: 8 rows x 128B per wave-call; linear dest, pre-swizzled source
  const int srow = l >> 3, spc = l & 7;
  auto stage_dma = [&](char* dstbase, const u16* Op, int o0, int r0, int kt) {
    const int row = r0 + srow;
    const int lc = spc ^ (row & 7);
    gl_lds16(Op + (size_t)(o0 + row) * 1024 + kt * 64 + lc * 8,
             (u16*)(dstbase + r0 * 128));
  };
  auto stageB = [&](int buf, int kt) {
#pragma unroll
    for (int i = 0; i < 4; ++i)
      stage_dma(BSM + buf * BBUF, B, n0, i * 32 + w * 8, kt);
  };
  auto stageA_dma = [&](int buf, int kt) {   // bf16 A source (outproj)
#pragma unroll
    for (int i = 0; i < BM / 32; ++i)
      stage_dma(ASM + buf * ABUF, (const u16*)Av, m0, i * 32 + w * 8, kt);
  };
  // fp32 A (proj): each pass covers 32 rows; lane owns (row, 8 consecutive k)
  f32x4 ar[4][2];
  auto stageA_load = [&](int kt) {
    const float* A = (const float*)Av;
#pragma unroll
    for (int p = 0; p < 4; ++p) {
      const int row = p * 32 + w * 8 + srow;
      const float* src = A + (size_t)(m0 + row) * 1024 + kt * 64 + spc * 8;
      ar[p][0] = *(const f32x4*)src;
      ar[p][1] = *(const f32x4*)(src + 4);
    }
  };
  auto stageA_write = [&](int buf) {
#pragma unroll
    for (int p = 0; p < 4; ++p) {
      const int row = p * 32 + w * 8 + srow;
      u16x8 v;
#pragma unroll
      for (int j = 0; j < 4; ++j) { v[j] = bfc(ar[p][0][j]); v[4 + j] = bfc(ar[p][1][j]); }
      *(u16x8*)(ASM + buf * ABUF + row * 128 + ((spc ^ (row & 7)) << 4)) = v;
    }
  };

  // hoisted frag byte-offsets: chunk = ks*4 + lg, phys = chunk ^ (row&7)
  int afo[MI][2], bfo[4][2];
#pragma unroll
  for (int i = 0; i < MI; ++i) {
    const int arow = wm + i * 16 + lr;
#pragma unroll
    for (int ks = 0; ks < 2; ++ks)
      afo[i][ks] = arow * 128 + (((ks * 4 + lg) ^ (arow & 7)) << 4);
  }
#pragma unroll
  for (int i = 0; i < 4; ++i) {
    const int brow = wn + i * 16 + lr;
#pragma unroll
    for (int ks = 0; ks < 2; ++ks)
      bfo[i][ks] = brow * 128 + (((ks * 4 + lg) ^ (brow & 7)) << 4);
  }

  f32x4 acc[MI][4];
#pragma unroll
  for (int i = 0; i < MI; ++i)
#pragma unroll
    for (int j = 0; j < 4; ++j) acc[i][j] = f32x4{0.f, 0.f, 0.f, 0.f};

  if constexpr (AREG) { stageA_load(0); stageA_write(0); }
  else                stageA_dma(0, 0);
  stageB(0, 0);

  for (int kt = 0; kt < NK; ++kt) {
    const int buf = kt & 1;
    __syncthreads();
    if (kt + 1 < NK) {
      if constexpr (AREG) stageA_load(kt + 1);   // issue early; latency under MFMAs
      else                stageA_dma(buf ^ 1, kt + 1);
      stageB(buf ^ 1, kt + 1);
    }
#pragma unroll
    for (int ks = 0; ks < 2; ++ks) {
      bf16x8 af[MI], bfr[4];
#pragma unroll
      for (int i = 0; i < MI; ++i)
        af[i] = *(const bf16x8*)(ASM + buf * ABUF + afo[i][ks]);
#pragma unroll
      for (int i = 0; i < 4; ++i)
        bfr[i] = *(const bf16x8*)(BSM + buf * BBUF + bfo[i][ks]);
#pragma unroll
      for (int mi = 0; mi < MI; ++mi)
#pragma unroll
        for (int ni = 0; ni < 4; ++ni)
          acc[mi][ni] = __builtin_amdgcn_mfma_f32_16x16x32_bf16(af[mi], bfr[ni], acc[mi][ni], 0, 0, 0);
    }
    if (kt + 1 < NK) {
      if constexpr (AREG) stageA_write(buf ^ 1);  // write late, under MFMA shadow
    }
  }

  float bv[4];
#pragma unroll
  for (int ni = 0; ni < 4; ++ni) bv[ni] = bias[n0 + wn + ni * 16 + lr];

  if constexpr (MODE != 2) {
#pragma unroll
    for (int mi = 0; mi < MI; ++mi)
#pragma unroll
      for (int ni = 0; ni < 4; ++ni)
#pragma unroll
        for (int r = 0; r < 4; ++r) {
          const int row = m0 + wm + mi * 16 + lg * 4 + r;
          const int col = n0 + wn + ni * 16 + lr;
          float vv = (acc[mi][ni][r] + bv[ni]) * scale;
          if constexpr (MODE == 1) ((float*)Cv)[(size_t)row * N + col] = vv;
          else                     ((u16*)Cv)[(size_t)row * N + col] = f2bf(vv);
        }
  } else {
    // V^T epilogue: transpose 64x64 wave quadrant through LDS (reuse arena),
    // then coalesced 16B stores (8 lanes cover one contiguous 128B d-row).
    __syncthreads();                      // all waves done reading As/Bs
    char* wb = SMraw + w * 8192;          // per-wave [64 d][64 s] bf16, 128B rows
#pragma unroll
    for (int mi = 0; mi < MI; ++mi)
#pragma unroll
      for (int ni = 0; ni < 4; ++ni)
#pragma unroll
        for (int r = 0; r < 4; ++r) {
          const int dl = ni * 16 + lr;
          const int sl = mi * 16 + lg * 4 + r;
          const int phys = (sl >> 3) ^ (lr & 7);   // chunk-XOR keyed by d&7
          *(u16*)(wb + dl * 128 + (phys << 4) + (sl & 7) * 2) =
              f2bf(acc[mi][ni][r] + bv[ni]);
        }
    // intra-wave RAW through LDS; read rows [d][s], store 16B chunks
    const int sc2 = l & 7, srl2 = l >> 3;
    const int rowg = m0 + wm;             // s base (same b for whole quadrant)
#pragma unroll
    for (int i = 0; i < 8; ++i) {
      const int dl = i * 8 + srl2;
      const int phys = sc2 ^ srl2;        // dl&7 == srl2
      u16x8 vrow = *(u16x8*)(wb + dl * 128 + (phys << 4));
      const int colg = n0 + wn + dl;
      u16* dst = (u16*)Cv + ((size_t)((rowg >> 11) << 10) + colg) * 2048 +
                 (rowg & 2047) + sc2 * 8;
      *(u16x8*)dst = vrow;
    }
  }
}

__global__ __launch_bounds__(256, 2)
void proj_kernel(const float* __restrict__ q, const float* __restrict__ k, const float* __restrict__ v,
                 const u16* __restrict__ wqb, const u16* __restrict__ wkb, const u16* __restrict__ wvb,
                 const float* __restrict__ bq, const float* __restrict__ bk, const float* __restrict__ bvv,
                 u16* __restrict__ qh, u16* __restrict__ kh, u16* __restrict__ vt) {
  __shared__ __align__(16) char SM[65536];   // A dbuf 32KB + B dbuf 32KB
  // Q gets scale log2(e)/32 so attention scores feed exp2 directly
  if (blockIdx.z == 0)      gemm_body<0, 128, true>(q, wqb, bq, qh, 1.44269504089f / 32.f, SM);
  else if (blockIdx.z == 1) gemm_body<0, 128, true>(k, wkb, bk, kh, 1.0f, SM);
  else                      gemm_body<2, 128, true>(v, wvb, bvv, vt, 1.0f, SM);
}

__global__ __launch_bounds__(256, 2)
void outproj_kernel(const u16* __restrict__ attnb, const u16* __restrict__ wob,
                    const float* __restrict__ bo, float* __restrict__ out) {
  __shared__ __align__(16) char SM[49152];   // A dbuf 16KB + B dbuf 32KB
  gemm_body<1, 64, false>(attnb, wob, bo, out, 1.0f, SM);
}

// ---------------- flash attention: in-register P (swapped QK + row-permuted K)
// grid (32 bh, 16 qt). 4 waves, wave w owns 32 q-rows (2 qh halves).
// QK computed as mfma(K, Q) -> C col = lane = q: each lane's 16 scores are all
// for ONE q-row = the PV A-frag ownership. K-tile staged with row bit-permute
// k = [b5 b3 b2 b4 b1 b0] so lane-local k-quads become the NATURAL contiguous
// mapping kappa(lg,j) = win*32 + lg*8 + j -> V's conflict-free b128 reads match
// unchanged. P = exp2(sfr) built directly into MFMA A-frags; NO P LDS traffic.
__global__ __launch_bounds__(256, 2)
void attn_kernel(const u16* __restrict__ Q, const u16* __restrict__ Kh,
                 const u16* __restrict__ Vt, u16* __restrict__ Ao) {
  constexpr int E = 1024, S = 2048, NT = S / 64;
  const int bh = blockIdx.x, qt = blockIdx.y;
  const int b = bh >> 4, h = bh & 15;
  const int tid = threadIdx.x, w = tid >> 6, l = tid & 63;
  const int lr = l & 15, lg = l >> 4;

  // LDS arena: [0,16K) Ks[2][64][64]  [16K,32K) Vs[2][64][64]
  __shared__ __align__(16) char SM[32768];

  const u16* Qp = Q + (size_t)b * S * E + (size_t)h * 64;
  const u16* Kp = Kh + (size_t)b * S * E + (size_t)h * 64;
  const u16* Vp = Vt + (size_t)bh * 64 * S;   // [d][s]

  const int qbase = qt * 128 + w * 32;
  bf16x8 qa[2][2];
#pragma unroll
  for (int qh = 0; qh < 2; ++qh)
#pragma unroll
    for (int hh = 0; hh < 2; ++hh)
      qa[qh][hh] = *(const bf16x8*)(Qp + (size_t)(qbase + qh * 16 + lr) * E + hh * 32 + lg * 8);

  bf16x8 ones;
#pragma unroll
  for (int j = 0; j < 8; ++j) ones[j] = (__bf16)1.0f;

  f32x4 o_acc[2][4];      // [qh][nf]  : O[q=lg*4+r][d=nf*16+lr]
#pragma unroll
  for (int qh = 0; qh < 2; ++qh)
#pragma unroll
    for (int nf = 0; nf < 4; ++nf) o_acc[qh][nf] = f32x4{0.f, 0.f, 0.f, 0.f};
  f32x4 sum_acc[2] = {f32x4{0.f, 0.f, 0.f, 0.f}, f32x4{0.f, 0.f, 0.f, 0.f}};

  // ---- hoisted loop-invariant LDS byte offsets ----
  const int swz8 = lr & 7;
  int fofs0[4], fofs1[4];            // K/V fragment offsets (same tile geometry)
#pragma unroll
  for (int nf = 0; nf < 4; ++nf) {
    fofs0[nf] = (((nf * 16 + lr) * 64) + (lg ^ swz8) * 8) * 2;
    fofs1[nf] = (((nf * 16 + lr) * 64) + ((4 + lg) ^ swz8) * 8) * 2;
  }

  const int sc = l & 7, srl = l >> 3;
  // K staged-row bit-permute: staged row r' holds global k = [b5 b3 b2 b4 b1 b0]
  auto kperm = [](int r) {
    return (r & 35) | ((r & 12) << 1) | ((r & 16) >> 2);
  };
  auto stageK = [&](int buf, int kb) {
#pragma unroll
    for (int i = 0; i < 2; ++i) {
      const int row = i * 32 + w * 8 + srl;
      const int cp = sc ^ (row & 7);
      gl_lds16(Kp + (size_t)(kb + kperm(row)) * E + cp * 8,
               (u16*)(SM + buf * 8192 + (i * 32 + w * 8) * 128));
    }
  };
  auto stageV = [&](int buf, int kb) {
#pragma unroll
    for (int i = 0; i < 2; ++i) {
      const int row = i * 32 + w * 8 + srl;
      const int cp = sc ^ (row & 7);
      gl_lds16(Vp + (size_t)row * S + kb + cp * 8,
               (u16*)(SM + 16384 + buf * 8192 + (i * 32 + w * 8) * 128));
    }
  };

  stageK(0, 0); stageV(0, 0);
  for (int t = 0; t < NT; ++t) {
    const int cur = t & 1;
    __syncthreads();                           // buf[cur] ready; prior reads drained
    if (t + 1 < NT) { stageK(cur ^ 1, (t + 1) * 64); stageV(cur ^ 1, (t + 1) * 64); }
    const char* Kc = SM + cur * 8192;
    const char* Vc = SM + 16384 + cur * 8192;

    // swapped QK^T: sfr[qh][nf], lane holds S[k'][q = qh*16 + lr]; staged-row
    // permute makes lane-local quads contiguous: k of sfr[nf][r]
    // = (nf>>1)*32 + lg*8 + (nf&1)*4 + r
    f32x4 sfr[2][4];
    __builtin_amdgcn_s_setprio(1);
#pragma unroll
    for (int nf = 0; nf < 4; ++nf) {
      bf16x8 k0 = *(const bf16x8*)(Kc + fofs0[nf]);
      bf16x8 k1 = *(const bf16x8*)(Kc + fofs1[nf]);
#pragma unroll
      for (int qh = 0; qh < 2; ++qh) {
        f32x4 z = f32x4{0.f, 0.f, 0.f, 0.f};
        z = __builtin_amdgcn_mfma_f32_16x16x32_bf16(k0, qa[qh][0], z, 0, 0, 0);
        sfr[qh][nf] = __builtin_amdgcn_mfma_f32_16x16x32_bf16(k1, qa[qh][1], z, 0, 0, 0);
      }
    }
    __builtin_amdgcn_s_setprio(0);

    // P = exp2(s) packed straight into MFMA A-frags (no LDS):
    // pa0[qh] = k-window 0..31 (nf0 elems 0-3, nf1 elems 4-7); pa1 = 32..63
    bf16x8 pa0[2], pa1[2];
#pragma unroll
    for (int qh = 0; qh < 2; ++qh)
#pragma unroll
      for (int r = 0; r < 4; ++r) {
        pa0[qh][r]     = (__bf16)EXP2(sfr[qh][0][r]);
        pa0[qh][4 + r] = (__bf16)EXP2(sfr[qh][1][r]);
        pa1[qh][r]     = (__bf16)EXP2(sfr[qh][2][r]);
        pa1[qh][4 + r] = (__bf16)EXP2(sfr[qh][3][r]);
      }

    // denominators via ones-MFMA (sums all 32 k-slots per window)
#pragma unroll
    for (int qh = 0; qh < 2; ++qh) {
      sum_acc[qh] = __builtin_amdgcn_mfma_f32_16x16x32_bf16(pa0[qh], ones, sum_acc[qh], 0, 0, 0);
      sum_acc[qh] = __builtin_amdgcn_mfma_f32_16x16x32_bf16(pa1[qh], ones, sum_acc[qh], 0, 0, 0);
    }

    // PV: V b128 frags (conflict-free, same fofs), each feeds both qh halves
    __builtin_amdgcn_s_setprio(1);
#pragma unroll
    for (int nf = 0; nf < 4; ++nf) {
      bf16x8 vb0 = *(const bf16x8*)(Vc + fofs0[nf]);
      bf16x8 vb1 = *(const bf16x8*)(Vc + fofs1[nf]);
#pragma unroll
      for (int qh = 0; qh < 2; ++qh) {
        o_acc[qh][nf] = __builtin_amdgcn_mfma_f32_16x16x32_bf16(pa0[qh], vb0, o_acc[qh][nf], 0, 0, 0);
        o_acc[qh][nf] = __builtin_amdgcn_mfma_f32_16x16x32_bf16(pa1[qh], vb1, o_acc[qh][nf], 0, 0, 0);
      }
    }
    __builtin_amdgcn_s_setprio(0);
  }

#pragma unroll
  for (int qh = 0; qh < 2; ++qh)
#pragma unroll
    for (int r = 0; r < 4; ++r) {
      const float inv = 1.0f / sum_acc[qh][r];
      const size_t row = (size_t)b * S + qbase + qh * 16 + lg * 4 + r;
#pragma unroll
      for (int nf = 0; nf < 4; ++nf)
        Ao[row * E + h * 64 + nf * 16 + lr] = f2bf(o_acc[qh][nf][r] * inv);
    }
}

// ---------------- launch ----------------
extern "C" void kernel_launch(void* const* d_in, const int* in_sizes, int n_in,
                              void* d_out, int out_size, void* d_ws, size_t ws_size,
                              hipStream_t stream) {
  const float* q  = (const float*)d_in[0];
  const float* k  = (const float*)d_in[1];
  const float* v  = (const float*)d_in[2];
  const float* Wq = (const float*)d_in[3];
  const float* bq = (const float*)d_in[4];
  const float* Wk = (const float*)d_in[5];
  const float* bk = (const float*)d_in[6];
  const float* Wv = (const float*)d_in[7];
  const float* bv = (const float*)d_in[8];
  const float* Wo = (const float*)d_in[9];
  const float* bo = (const float*)d_in[10];
  float* out = (float*)d_out;

  char* ws = (char*)d_ws;
  u16* attnb = (u16*)(ws);                     // 8MB (attn output, bf16)
  u16* wqb = (u16*)(ws + (24u << 20));         // 1M elems, 2MB each
  u16* wkb = (u16*)(ws + (26u << 20));
  u16* wvb = (u16*)(ws + (28u << 20));
  u16* wob = (u16*)(ws + (30u << 20));
  u16* qhp = (u16*)(ws + (32u << 20));         // 8MB each
  u16* khp = (u16*)(ws + (40u << 20));
  u16* vtp = (u16*)(ws + (48u << 20));         // V^T [b,h,d,s]

  cast_kernel<<<dim3(4096), dim3(256), 0, stream>>>(Wq, Wk, Wv, Wo, wqb, wkb, wvb, wob);
  proj_kernel<<<dim3(32, 8, 3), dim3(256), 0, stream>>>(q, k, v, wqb, wkb, wvb,
                                                        bq, bk, bv, qhp, khp, vtp);
  attn_kernel<<<dim3(32, 16), dim3(256), 0, stream>>>(qhp, khp, vtp, attnb);
  outproj_kernel<<<dim3(64, 8), dim3(256), 0, stream>>>(attnb, wob, bo, out);
}

// Round 21
// 103.682 us; speedup vs baseline: 1.0416x; 1.0416x over previous
//
#include <hip/hip_runtime.h>

// B=2, S=2048, E=1024, HEADS=16, HEAD_SIZE=64
// out = softmax((q Wq^T + bq)(k Wk^T + bk)^T / 32) (v Wv^T + bv) Wo^T + bo

typedef unsigned short u16;
typedef __bf16 bf16x8 __attribute__((ext_vector_type(8)));
typedef float f32x4 __attribute__((ext_vector_type(4)));
typedef u16 u16x4 __attribute__((ext_vector_type(4)));
typedef u16 u16x8 __attribute__((ext_vector_type(8)));

typedef __attribute__((address_space(1))) const unsigned int as1_cu32;
typedef __attribute__((address_space(3))) unsigned int as3_u32;

#if __has_builtin(__builtin_amdgcn_exp2f)
#define EXP2(x) __builtin_amdgcn_exp2f(x)   // raw v_exp_f32 (inputs are normal-range)
#else
#define EXP2(x) exp2f(x)
#endif

__device__ __forceinline__ u16 f2bf(float f) {
  unsigned u = __builtin_bit_cast(unsigned, f);
  u += 0x7fffu + ((u >> 16) & 1u);   // RTNE
  return (u16)(u >> 16);
}

__device__ __forceinline__ u16 bfc(float f) {   // RTNE via v_cvt (same bits as f2bf)
  return __builtin_bit_cast(u16, (__bf16)f);
}

__device__ __forceinline__ void gl_lds16(const u16* g, u16* l) {
  // async global->LDS, 16B/lane; LDS dest = wave-uniform base + lane*16
  __builtin_amdgcn_global_load_lds((as1_cu32*)g, (as3_u32*)l, 16, 0, 0);
}

// GEMM tile layout (bank-conflict-free): logical [R rows][32 k] bf16 packed as
// [R/2 LDS rows][128B]; LDS row j = global rows {2j, 2j+1}, 8 x 16B chunks,
// phys_chunk = ((grow&1)*4 + kchunk) ^ (j&7).  Frag/stage access = 2-way max.
__device__ __forceinline__ int tofs(int grow, int kchunk) {
  const int j = grow >> 1;
  return j * 128 + ((((grow & 1) * 4 + kchunk) ^ (j & 7)) << 4);
}

// ---------------- fp32 -> bf16 cast (4 weight matrices only) ----------------
__global__ void cast_kernel(const float* __restrict__ wq, const float* __restrict__ wk,
                            const float* __restrict__ wv, const float* __restrict__ wo,
                            u16* __restrict__ wqb, u16* __restrict__ wkb,
                            u16* __restrict__ wvb, u16* __restrict__ wob) {
  unsigned t = blockIdx.x * 256u + threadIdx.x;  // 1M float4 = 4 x 256K
  unsigned which = t >> 18, off = t & 262143u;
  const float* src = which == 0 ? wq : (which == 1 ? wk : (which == 2 ? wv : wo));
  u16* dst = which == 0 ? wqb : (which == 1 ? wkb : (which == 2 ? wvb : wob));
  float4 f = ((const float4*)src)[off];
  u16x4 o;
  o[0] = f2bf(f.x); o[1] = f2bf(f.y); o[2] = f2bf(f.z); o[3] = f2bf(f.w);
  ((u16x4*)dst)[off] = o;
}

// ---------------- NT GEMM: C = scale*(A B^T + bias) ----------------
// BM x 128 tile, BK=32, 4 waves, 16x16x32 MFMA, dbuf LDS (swizzled layout).
// AREG: A source is fp32; staged via regs (dwordx4 loads issued early, RTNE
// cvt to bf16, ds_write_b128 late) into the swizzled layout.
// MODE: 0 = bf16 row-major out, 1 = f32 row-major out,
// MODE 2 = bf16 V^T out [b,h,d,s] via LDS transpose + coalesced 16B stores.
template <int MODE, int BM, bool AREG>
__device__ __forceinline__ void gemm_body(const void* __restrict__ Av, const u16* __restrict__ B,
                                          const float* __restrict__ bias, void* __restrict__ Cv,
                                          float scale, char* SMraw) {
  constexpr int MI = BM / 32;                              // M frags per wave
  constexpr int ABUF = BM * 64;                            // bytes per A buffer (bf16)
  char* ASM = SMraw;
  char* BSM = SMraw + 2 * ABUF;                            // [2][8KB]
  constexpr int N = 1024, NK = 32;
  const int m0 = blockIdx.x * BM;
  const int n0 = blockIdx.y * 128;
  const int tid = threadIdx.x;
  const int w = tid >> 6, l = tid & 63;
  const int lr = l & 15, lg = l >> 4;
  const int wm = (w >> 1) * (BM / 2), wn = (w & 1) * 64;

  // DMA staging: linear 1KB per wave-issue; source pre-swizzled (inverse map)
  const int jof = l >> 3, pc = l & 7;
  auto stage_dma = [&](char* dstbase, const u16* Op, int o0, int r0, int kt) {
    const int j = (r0 >> 1) + jof;
    const int lc = pc ^ (j & 7);
    const int g = 2 * j + (lc >> 2);
    gl_lds16(Op + (size_t)(o0 + g) * 1024 + kt * 32 + (lc & 3) * 8,
             (u16*)(dstbase + (r0 >> 1) * 128));
  };
  auto stageB = [&](int buf, int kt) {
#pragma unroll
    for (int i = 0; i < 2; ++i)
      stage_dma(BSM + buf * 8192, B, n0, i * 64 + w * 16, kt);
  };
  auto stageA_dma = [&](int buf, int kt) {   // bf16 A source (outproj)
#pragma unroll
    for (int i = 0; i < BM / 64; ++i)
      stage_dma(ASM + buf * ABUF, (const u16*)Av, m0, i * 64 + w * 16, kt);
  };
  // fp32 A: issue loads early...
  f32x4 ar[BM / 64][2];
  auto stageA_load = [&](int kt) {
    const float* A = (const float*)Av;
#pragma unroll
    for (int i = 0; i < BM / 64; ++i) {
      const float* src = A + (size_t)(m0 + i * 64 + w * 16 + (l >> 2)) * 1024 + kt * 32 + (l & 3) * 8;
      ar[i][0] = *(const f32x4*)src;
      ar[i][1] = *(const f32x4*)(src + 4);
    }
  };
  // ...convert + write late into the swizzled layout
  auto stageA_write = [&](int buf) {
#pragma unroll
    for (int i = 0; i < BM / 64; ++i) {
      u16x8 v;
#pragma unroll
      for (int j = 0; j < 4; ++j) { v[j] = bfc(ar[i][0][j]); v[4 + j] = bfc(ar[i][1][j]); }
      *(u16x8*)(ASM + buf * ABUF + tofs(i * 64 + w * 16 + (l >> 2), l & 3)) = v;
    }
  };

  // hoisted frag byte-offsets (kchunk = lg)
  int afo[MI], bfo[4];
#pragma unroll
  for (int i = 0; i < MI; ++i) afo[i] = tofs(wm + i * 16 + lr, lg);
#pragma unroll
  for (int i = 0; i < 4; ++i) bfo[i] = tofs(wn + i * 16 + lr, lg);

  f32x4 acc[MI][4];
#pragma unroll
  for (int i = 0; i < MI; ++i)
#pragma unroll
    for (int j = 0; j < 4; ++j) acc[i][j] = f32x4{0.f, 0.f, 0.f, 0.f};

  if constexpr (AREG) { stageA_load(0); stageA_write(0); }
  else                stageA_dma(0, 0);
  stageB(0, 0);

  for (int kt = 0; kt < NK; ++kt) {
    const int buf = kt & 1;
    __syncthreads();
    if (kt + 1 < NK) {
      if constexpr (AREG) stageA_load(kt + 1);   // issue early; HBM/L2 latency
      else                stageA_dma(buf ^ 1, kt + 1);
      stageB(buf ^ 1, kt + 1);
    }
    bf16x8 af[MI], bfr[4];
#pragma unroll
    for (int i = 0; i < MI; ++i)
      af[i] = *(const bf16x8*)(ASM + buf * ABUF + afo[i]);
#pragma unroll
    for (int i = 0; i < 4; ++i)
      bfr[i] = *(const bf16x8*)(BSM + buf * 8192 + bfo[i]);
#pragma unroll
    for (int mi = 0; mi < MI; ++mi)
#pragma unroll
      for (int ni = 0; ni < 4; ++ni)
        acc[mi][ni] = __builtin_amdgcn_mfma_f32_16x16x32_bf16(af[mi], bfr[ni], acc[mi][ni], 0, 0, 0);
    if (kt + 1 < NK) {
      if constexpr (AREG) stageA_write(buf ^ 1);  // write late, under MFMA shadow
    }
  }

  float bv[4];
#pragma unroll
  for (int ni = 0; ni < 4; ++ni) bv[ni] = bias[n0 + wn + ni * 16 + lr];

  if constexpr (MODE != 2) {
#pragma unroll
    for (int mi = 0; mi < MI; ++mi)
#pragma unroll
      for (int ni = 0; ni < 4; ++ni)
#pragma unroll
        for (int r = 0; r < 4; ++r) {
          const int row = m0 + wm + mi * 16 + lg * 4 + r;
          const int col = n0 + wn + ni * 16 + lr;
          float vv = (acc[mi][ni][r] + bv[ni]) * scale;
          if constexpr (MODE == 1) ((float*)Cv)[(size_t)row * N + col] = vv;
          else                     ((u16*)Cv)[(size_t)row * N + col] = f2bf(vv);
        }
  } else {
    // V^T epilogue: transpose 64x64 wave quadrant through LDS (reuse arena),
    // then coalesced 16B stores (8 lanes cover one contiguous 128B d-row).
    __syncthreads();                      // all waves done reading As/Bs
    char* wb = SMraw + w * 8192;          // per-wave [64 d][64 s] bf16, 128B rows
#pragma unroll
    for (int mi = 0; mi < MI; ++mi)
#pragma unroll
      for (int ni = 0; ni < 4; ++ni)
#pragma unroll
        for (int r = 0; r < 4; ++r) {
          const int dl = ni * 16 + lr;
          const int sl = mi * 16 + lg * 4 + r;
          const int phys = (sl >> 3) ^ (lr & 7);   // chunk-XOR keyed by d&7
          *(u16*)(wb + dl * 128 + (phys << 4) + (sl & 7) * 2) =
              f2bf(acc[mi][ni][r] + bv[ni]);
        }
    // intra-wave RAW through LDS; read rows [d][s], store 16B chunks
    const int sc2 = l & 7, srl2 = l >> 3;
    const int rowg = m0 + wm;             // s base (same b for whole quadrant)
#pragma unroll
    for (int i = 0; i < 8; ++i) {
      const int dl = i * 8 + srl2;
      const int phys = sc2 ^ srl2;        // dl&7 == srl2
      u16x8 vrow = *(u16x8*)(wb + dl * 128 + (phys << 4));
      const int colg = n0 + wn + dl;
      u16* dst = (u16*)Cv + ((size_t)((rowg >> 11) << 10) + colg) * 2048 +
                 (rowg & 2047) + sc2 * 8;
      *(u16x8*)dst = vrow;
    }
  }
}

__global__ __launch_bounds__(256, 3)
void proj_kernel(const float* __restrict__ q, const float* __restrict__ k, const float* __restrict__ v,
                 const u16* __restrict__ wqb, const u16* __restrict__ wkb, const u16* __restrict__ wvb,
                 const float* __restrict__ bq, const float* __restrict__ bk, const float* __restrict__ bvv,
                 u16* __restrict__ qh, u16* __restrict__ kh, u16* __restrict__ vt) {
  __shared__ __align__(16) char SM[32768];   // A bf16 16KB + B 16KB
  // Q gets scale log2(e)/32 so attention scores feed exp2 directly
  if (blockIdx.z == 0)      gemm_body<0, 128, true>(q, wqb, bq, qh, 1.44269504089f / 32.f, SM);
  else if (blockIdx.z == 1) gemm_body<0, 128, true>(k, wkb, bk, kh, 1.0f, SM);
  else                      gemm_body<2, 128, true>(v, wvb, bvv, vt, 1.0f, SM);
}

__global__ __launch_bounds__(256, 2)
void outproj_kernel(const u16* __restrict__ attnb, const u16* __restrict__ wob,
                    const float* __restrict__ bo, float* __restrict__ out) {
  __shared__ __align__(16) char SM[24576];   // As 8KB + Bs 16KB
  gemm_body<1, 64, false>(attnb, wob, bo, out, 1.0f, SM);
}

// ---------------- flash attention: in-register P (swapped QK + row-permuted K)
// grid (32 bh, 16 qt). 4 waves, wave w owns 32 q-rows (2 qh halves).
// QK computed as mfma(K, Q) -> C col = lane = q: each lane's 16 scores are all
// for ONE q-row = the PV A-frag ownership. K-tile staged with row bit-permute
// k = [b5 b3 b2 b4 b1 b0] so lane-local k-quads become the NATURAL contiguous
// mapping kappa(lg,j) = win*32 + lg*8 + j -> V's conflict-free b128 reads match
// unchanged. P = exp2(sfr) built directly into MFMA A-frags; NO P LDS traffic.
__global__ __launch_bounds__(256, 2)
void attn_kernel(const u16* __restrict__ Q, const u16* __restrict__ Kh,
                 const u16* __restrict__ Vt, u16* __restrict__ Ao) {
  constexpr int E = 1024, S = 2048, NT = S / 64;
  const int bh = blockIdx.x, qt = blockIdx.y;
  const int b = bh >> 4, h = bh & 15;
  const int tid = threadIdx.x, w = tid >> 6, l = tid & 63;
  const int lr = l & 15, lg = l >> 4;

  // LDS arena: [0,16K) Ks[2][64][64]  [16K,32K) Vs[2][64][64]
  __shared__ __align__(16) char SM[32768];

  const u16* Qp = Q + (size_t)b * S * E + (size_t)h * 64;
  const u16* Kp = Kh + (size_t)b * S * E + (size_t)h * 64;
  const u16* Vp = Vt + (size_t)bh * 64 * S;   // [d][s]

  const int qbase = qt * 128 + w * 32;
  bf16x8 qa[2][2];
#pragma unroll
  for (int qh = 0; qh < 2; ++qh)
#pragma unroll
    for (int hh = 0; hh < 2; ++hh)
      qa[qh][hh] = *(const bf16x8*)(Qp + (size_t)(qbase + qh * 16 + lr) * E + hh * 32 + lg * 8);

  bf16x8 ones;
#pragma unroll
  for (int j = 0; j < 8; ++j) ones[j] = (__bf16)1.0f;

  f32x4 o_acc[2][4];      // [qh][nf]  : O[q=lg*4+r][d=nf*16+lr]
#pragma unroll
  for (int qh = 0; qh < 2; ++qh)
#pragma unroll
    for (int nf = 0; nf < 4; ++nf) o_acc[qh][nf] = f32x4{0.f, 0.f, 0.f, 0.f};
  f32x4 sum_acc[2] = {f32x4{0.f, 0.f, 0.f, 0.f}, f32x4{0.f, 0.f, 0.f, 0.f}};

  // ---- hoisted loop-invariant LDS byte offsets ----
  const int swz8 = lr & 7;
  int fofs0[4], fofs1[4];            // K/V fragment offsets (same tile geometry)
#pragma unroll
  for (int nf = 0; nf < 4; ++nf) {
    fofs0[nf] = (((nf * 16 + lr) * 64) + (lg ^ swz8) * 8) * 2;
    fofs1[nf] = (((nf * 16 + lr) * 64) + ((4 + lg) ^ swz8) * 8) * 2;
  }

  const int sc = l & 7, srl = l >> 3;
  // K staged-row bit-permute: staged row r' holds global k = [b5 b3 b2 b4 b1 b0]
  auto kperm = [](int r) {
    return (r & 35) | ((r & 12) << 1) | ((r & 16) >> 2);
  };
  auto stageK = [&](int buf, int kb) {
#pragma unroll
    for (int i = 0; i < 2; ++i) {
      const int row = i * 32 + w * 8 + srl;
      const int cp = sc ^ (row & 7);
      gl_lds16(Kp + (size_t)(kb + kperm(row)) * E + cp * 8,
               (u16*)(SM + buf * 8192 + (i * 32 + w * 8) * 128));
    }
  };
  auto stageV = [&](int buf, int kb) {
#pragma unroll
    for (int i = 0; i < 2; ++i) {
      const int row = i * 32 + w * 8 + srl;
      const int cp = sc ^ (row & 7);
      gl_lds16(Vp + (size_t)row * S + kb + cp * 8,
               (u16*)(SM + 16384 + buf * 8192 + (i * 32 + w * 8) * 128));
    }
  };

  stageK(0, 0); stageV(0, 0);
  for (int t = 0; t < NT; ++t) {
    const int cur = t & 1;
    __syncthreads();                           // buf[cur] ready; prior reads drained
    if (t + 1 < NT) { stageK(cur ^ 1, (t + 1) * 64); stageV(cur ^ 1, (t + 1) * 64); }
    const char* Kc = SM + cur * 8192;
    const char* Vc = SM + 16384 + cur * 8192;

    // swapped QK^T: sfr[qh][nf], lane holds S[k'][q = qh*16 + lr]; staged-row
    // permute makes lane-local quads contiguous: k of sfr[nf][r]
    // = (nf>>1)*32 + lg*8 + (nf&1)*4 + r
    f32x4 sfr[2][4];
    __builtin_amdgcn_s_setprio(1);
#pragma unroll
    for (int nf = 0; nf < 4; ++nf) {
      bf16x8 k0 = *(const bf16x8*)(Kc + fofs0[nf]);
      bf16x8 k1 = *(const bf16x8*)(Kc + fofs1[nf]);
#pragma unroll
      for (int qh = 0; qh < 2; ++qh) {
        f32x4 z = f32x4{0.f, 0.f, 0.f, 0.f};
        z = __builtin_amdgcn_mfma_f32_16x16x32_bf16(k0, qa[qh][0], z, 0, 0, 0);
        sfr[qh][nf] = __builtin_amdgcn_mfma_f32_16x16x32_bf16(k1, qa[qh][1], z, 0, 0, 0);
      }
    }
    __builtin_amdgcn_s_setprio(0);

    // P = exp2(s) packed straight into MFMA A-frags (no LDS):
    // pa0[qh] = k-window 0..31 (nf0 elems 0-3, nf1 elems 4-7); pa1 = 32..63
    bf16x8 pa0[2], pa1[2];
#pragma unroll
    for (int qh = 0; qh < 2; ++qh)
#pragma unroll
      for (int r = 0; r < 4; ++r) {
        pa0[qh][r]     = (__bf16)EXP2(sfr[qh][0][r]);
        pa0[qh][4 + r] = (__bf16)EXP2(sfr[qh][1][r]);
        pa1[qh][r]     = (__bf16)EXP2(sfr[qh][2][r]);
        pa1[qh][4 + r] = (__bf16)EXP2(sfr[qh][3][r]);
      }

    // denominators via ones-MFMA (sums all 32 k-slots per window)
#pragma unroll
    for (int qh = 0; qh < 2; ++qh) {
      sum_acc[qh] = __builtin_amdgcn_mfma_f32_16x16x32_bf16(pa0[qh], ones, sum_acc[qh], 0, 0, 0);
      sum_acc[qh] = __builtin_amdgcn_mfma_f32_16x16x32_bf16(pa1[qh], ones, sum_acc[qh], 0, 0, 0);
    }

    // PV: V b128 frags (conflict-free, same fofs), each feeds both qh halves
    __builtin_amdgcn_s_setprio(1);
#pragma unroll
    for (int nf = 0; nf < 4; ++nf) {
      bf16x8 vb0 = *(const bf16x8*)(Vc + fofs0[nf]);
      bf16x8 vb1 = *(const bf16x8*)(Vc + fofs1[nf]);
#pragma unroll
      for (int qh = 0; qh < 2; ++qh) {
        o_acc[qh][nf] = __builtin_amdgcn_mfma_f32_16x16x32_bf16(pa0[qh], vb0, o_acc[qh][nf], 0, 0, 0);
        o_acc[qh][nf] = __builtin_amdgcn_mfma_f32_16x16x32_bf16(pa1[qh], vb1, o_acc[qh][nf], 0, 0, 0);
      }
    }
    __builtin_amdgcn_s_setprio(0);
  }

#pragma unroll
  for (int qh = 0; qh < 2; ++qh)
#pragma unroll
    for (int r = 0; r < 4; ++r) {
      const float inv = 1.0f / sum_acc[qh][r];
      const size_t row = (size_t)b * S + qbase + qh * 16 + lg * 4 + r;
#pragma unroll
      for (int nf = 0; nf < 4; ++nf)
        Ao[row * E + h * 64 + nf * 16 + lr] = f2bf(o_acc[qh][nf][r] * inv);
    }
}

// ---------------- launch ----------------
extern "C" void kernel_launch(void* const* d_in, const int* in_sizes, int n_in,
                              void* d_out, int out_size, void* d_ws, size_t ws_size,
                              hipStream_t stream) {
  const float* q  = (const float*)d_in[0];
  const float* k  = (const float*)d_in[1];
  const float* v  = (const float*)d_in[2];
  const float* Wq = (const float*)d_in[3];
  const float* bq = (const float*)d_in[4];
  const float* Wk = (const float*)d_in[5];
  const float* bk = (const float*)d_in[6];
  const float* Wv = (const float*)d_in[7];
  const float* bv = (const float*)d_in[8];
  const float* Wo = (const float*)d_in[9];
  const float* bo = (const float*)d_in[10];
  float* out = (float*)d_out;

  char* ws = (char*)d_ws;
  u16* attnb = (u16*)(ws);                     // 8MB (attn output, bf16)
  u16* wqb = (u16*)(ws + (24u << 20));         // 1M elems, 2MB each
  u16* wkb = (u16*)(ws + (26u << 20));
  u16* wvb = (u16*)(ws + (28u << 20));
  u16* wob = (u16*)(ws + (30u << 20));
  u16* qhp = (u16*)(ws + (32u << 20));         // 8MB each
  u16* khp = (u16*)(ws + (40u << 20));
  u16* vtp = (u16*)(ws + (48u << 20));         // V^T [b,h,d,s]

  cast_kernel<<<dim3(4096), dim3(256), 0, stream>>>(Wq, Wk, Wv, Wo, wqb, wkb, wvb, wob);
  proj_kernel<<<dim3(32, 8, 3), dim3(256), 0, stream>>>(q, k, v, wqb, wkb, wvb,
                                                        bq, bk, bv, qhp, khp, vtp);
  attn_kernel<<<dim3(32, 16), dim3(256), 0, stream>>>(qhp, khp, vtp, attnb);
  outproj_kernel<<<dim3(64, 8), dim3(256), 0, stream>>>(attnb, wob, bo, out);
}